// Round 3
// baseline (553.660 us; speedup 1.0000x reference)
//
#include <hip/hip_runtime.h>
#include <math.h>

// B=8, L=4096, H=8, E=64, MODES=64, C=512. Truncated DFT + tiny complex GEMMs + truncated iDFT.
// v, index_q, index_kv unused by the reference.

#define Lt 4096
#define Ct 512
#define Mt 64

// ws layout (float offsets)
#define TWA_OFF   0u                      // [1024 t][128]: cos,-sin per mode (512 KB)
#define TWJ_OFF   131072u                 // [128 j][4096 t]: j=2m -> cos, j=2m+1 -> +sin (2 MB)
#define QF_OFF    655360u                 // reduced qf: [2 src][8 b][64 m][512 c][2]  (4 MB)
#define COEF_OFF  9043968u                // coefT: [64 bh][128 j][64 o]  (2 MB)
// split-K partials qfp [32 chs][8 b][64 m][512 c][2] = 67,108,864 B live in d_out (exactly
// out_size); fully consumed by reduce_kernel before idft overwrites d_out.

__global__ __launch_bounds__(256) void init_tw(float* __restrict__ twa) {
  int id = blockIdx.x * 256 + threadIdx.x;   // 65536
  int t = id >> 6, m = id & 63;
  int idx = (m * t) & 4095;
  float a = (float)idx * (1.0f / 2048.0f);
  float s, c;
  sincospif(a, &s, &c);
  twa[t * 128 + 2 * m]     = c;
  twa[t * 128 + 2 * m + 1] = -s;
}

__global__ __launch_bounds__(256) void init_twj(float* __restrict__ twj) {
  int id = blockIdx.x * 256 + threadIdx.x;   // 524288
  int j = id >> 12, t = id & 4095;
  int m = j >> 1;
  int idx = (m * t) & 4095;
  float a = (float)idx * (1.0f / 2048.0f);
  float s, c;
  sincospif(a, &s, &c);
  twj[id] = (j & 1) ? s : c;
}

// Stage A: truncated DFT, radix-4 folded.
// R2 lesson: mode-split axis multiplies x re-reads (mg 4->8 tripled FETCH, regressed).
// So: mg stays 4 (L3-friendly), occupancy comes from t-split: ch 8->16 (64 iters/block).
// Grid 2048 = mg(2b)|ch(4b)|cblk(1b)|src(1b)|b(3b): 8192 waves = 8/SIMD (max).
// Slab sharers (same b,src,cblk,ch; 4 mg values) differ by 512 == 0 mod 8 -> same XCD L2.
__global__ __launch_bounds__(256, 8) void dft_kernel(const float* __restrict__ q,
                                                     const float* __restrict__ k,
                                                     const float* __restrict__ twa,
                                                     float* __restrict__ qfp) {
  const int id   = blockIdx.x;
  const int b    = id & 7;
  const int src  = (id >> 3) & 1;
  const int cblk = (id >> 4) & 1;
  const int ch   = (id >> 5) & 15;           // t-chunk (16 chunks of 64 iters)
  const int mg   = (id >> 9) & 3;            // mode quarter: modes [mg*16, mg*16+16)
  const int c    = cblk * 256 + threadIdx.x;
  const float* __restrict__ x = (src ? k : q) + (size_t)b * (Lt * Ct) + c;

  float acc[32];
#pragma unroll
  for (int j = 0; j < 32; ++j) acc[j] = 0.f;

  const int t0 = ch * 64;
  float n0 = x[(size_t)(t0)        * Ct];
  float n1 = x[(size_t)(t0 + 1024) * Ct];
  float n2 = x[(size_t)(t0 + 2048) * Ct];
  float n3 = x[(size_t)(t0 + 3072) * Ct];

  for (int t = t0; t < t0 + 64; ++t) {
    const float x0 = n0, x1 = n1, x2 = n2, x3 = n3;
    const int tn = (t + 1 < t0 + 64) ? (t + 1) : t0;
    n0 = x[(size_t)(tn)        * Ct];
    n1 = x[(size_t)(tn + 1024) * Ct];
    n2 = x[(size_t)(tn + 2048) * Ct];
    n3 = x[(size_t)(tn + 3072) * Ct];

    const float s02 = x0 + x2, s13 = x1 + x3;
    const float A0v = s02 + s13;
    const float A2v = s02 - s13;
    const float D0v = x0 - x2;
    const float D1v = x1 - x3;

    const float4* __restrict__ tw4 = (const float4*)(twa + t * 128 + mg * 32);  // wave-uniform
#pragma unroll
    for (int l = 0; l < 4; ++l) {          // 4 mode-quads of this quarter
      const float4 wa = tw4[2 * l + 0];    // modes 4l+0 (re,im), 4l+1 (re,im)
      const float4 wb = tw4[2 * l + 1];    // modes 4l+2, 4l+3
      // m%4==0: A0
      acc[8 * l + 0] = fmaf(A0v, wa.x, acc[8 * l + 0]);
      acc[8 * l + 1] = fmaf(A0v, wa.y, acc[8 * l + 1]);
      // m%4==1: (D0 - i D1)
      acc[8 * l + 2] = fmaf(D0v, wa.z, fmaf(D1v, wa.w, acc[8 * l + 2]));
      acc[8 * l + 3] = fmaf(D0v, wa.w, fmaf(-D1v, wa.z, acc[8 * l + 3]));
      // m%4==2: A2
      acc[8 * l + 4] = fmaf(A2v, wb.x, acc[8 * l + 4]);
      acc[8 * l + 5] = fmaf(A2v, wb.y, acc[8 * l + 5]);
      // m%4==3: (D0 + i D1)
      acc[8 * l + 6] = fmaf(D0v, wb.z, fmaf(-D1v, wb.w, acc[8 * l + 6]));
      acc[8 * l + 7] = fmaf(D0v, wb.w, fmaf(D1v, wb.z, acc[8 * l + 7]));
    }
  }

  const int chs = ch * 2 + src;              // 0..31
  float* __restrict__ outp = qfp + (size_t)(chs * 8 + b) * 65536 + (size_t)c * 2;
#pragma unroll
  for (int lm = 0; lm < 16; ++lm) {
    const int m = mg * 16 + lm;
    *(float2*)(outp + (size_t)m * 1024) = make_float2(acc[2 * lm], acc[2 * lm + 1]);
  }
}

// Reduce the 32 split-K partial chunks into dense qf[src][b][m][c][2] (4 MB).
// Pure memory-bound pass with full-GPU parallelism; removes partial-summing from the
// latency-starved attn load phase.
__global__ __launch_bounds__(256, 8) void reduce_kernel(const float* __restrict__ qfp,
                                                        float* __restrict__ qf) {
  const int gid = blockIdx.x * 256 + threadIdx.x;   // 262144 float4s
  const int src = gid >> 17;
  const int rem = gid & 131071;
  const int b   = rem >> 14;
  const int m   = (rem >> 8) & 63;
  const int c4  = rem & 255;

  const float4* __restrict__ in = (const float4*)qfp + (size_t)m * 256 + c4;
  float4 s = make_float4(0.f, 0.f, 0.f, 0.f);
#pragma unroll
  for (int ch = 0; ch < 16; ++ch) {
    const float4 v = in[(size_t)((ch * 2 + src) * 8 + b) * 16384];
    s.x += v.x; s.y += v.y; s.z += v.z; s.w += v.w;
  }
  ((float4*)qf)[(size_t)((src * 8 + b) * 64 + m) * 256 + c4] = s;
}

// Stage B: grid 512: each (b,h) split 8-way along Q-mode axis (xq owns modes [xq*8, xq*8+8)).
// Loads now hit the 4 MB qf (L2/L3-hot), 1 float2 per row. LDS float2 planes XOR-swizzled
// (row r, col c at r*64 + (c ^ (r&31))) -> <=2-way conflicts everywhere.
// id = b*64 + h*8 + xq: blocks sharing a w-slice (same h,xq) differ by 64 -> same XCD.
__global__ __launch_bounds__(256) void attn_kernel(const float* __restrict__ qf,
                                                   const float* __restrict__ w1,
                                                   const float* __restrict__ w2,
                                                   float* __restrict__ coefT) {
  __shared__ float2 KS[4096];   // K[y][e]; rows 0..7 later overwritten with P[xl][e]
  __shared__ float2 QS[512];    // Q[xl][e]; after B1 overwritten with S[xl][y]

  const int id = blockIdx.x;
  const int b  = id >> 6;
  const int h  = (id >> 3) & 7;
  const int xq = id & 7;
  const int bh = b * 8 + h;

  const int lane = threadIdx.x & 63;
  const int g    = threadIdx.x >> 6;

  // ---- load: K rows y (all 64), Q rows xl (8 of them) ----
#pragma unroll 4
  for (int it = 0; it < 16; ++it) {
    const int y = g + 4 * it;
    const float2 kv = *(const float2*)(qf + (size_t)(8 + b) * 65536 +
                                       (size_t)y * 1024 + (size_t)(h * 64 + lane) * 2);
    KS[y * 64 + (lane ^ (y & 31))] = kv;
  }
#pragma unroll
  for (int it = 0; it < 2; ++it) {
    const int xl = g + 4 * it;
    const int m  = xq * 8 + xl;
    const float2 qv = *(const float2*)(qf + (size_t)b * 65536 +
                                       (size_t)m * 1024 + (size_t)(h * 64 + lane) * 2);
    QS[xl * 64 + (lane ^ xl)] = qv;
  }
  __syncthreads();

  // ---- B1: thread (y=lane, g): S[xl][y] = sum_e Q[xl][e]*K[y][e], xl in {g*2, g*2+1} ----
  {
    const int y = lane;
    float sr[2], si[2];
#pragma unroll
    for (int i = 0; i < 2; ++i) { sr[i] = 0.f; si[i] = 0.f; }
    for (int e = 0; e < 64; ++e) {
      const float2 kv = KS[y * 64 + (e ^ (y & 31))];
#pragma unroll
      for (int xi = 0; xi < 2; ++xi) {
        const int xl = g * 2 + xi;
        const float2 qv = QS[xl * 64 + (e ^ xl)];     // wave-uniform -> broadcast
        sr[xi] = fmaf(qv.x, kv.x, fmaf(-qv.y, kv.y, sr[xi]));
        si[xi] = fmaf(qv.x, kv.y, fmaf(qv.y, kv.x, si[xi]));
      }
    }
    __syncthreads();
#pragma unroll
    for (int xi = 0; xi < 2; ++xi) {
      const int xl = g * 2 + xi;
      QS[xl * 64 + (y ^ xl)] = make_float2(tanhf(sr[xi]), tanhf(si[xi]));
    }
  }
  __syncthreads();

  // ---- B2: thread (e=lane, g): P[xl][e] = sum_y S[xl][y]*K[y][e] ----
  {
    const int e = lane;
    float pr[2], pi[2];
#pragma unroll
    for (int i = 0; i < 2; ++i) { pr[i] = 0.f; pi[i] = 0.f; }
    for (int y = 0; y < 64; ++y) {
      const float2 kv = KS[y * 64 + (e ^ (y & 31))];
#pragma unroll
      for (int xi = 0; xi < 2; ++xi) {
        const int xl = g * 2 + xi;
        const float2 sv = QS[xl * 64 + (y ^ xl)];     // wave-uniform -> broadcast
        pr[xi] = fmaf(sv.x, kv.x, fmaf(-sv.y, kv.y, pr[xi]));
        pi[xi] = fmaf(sv.x, kv.y, fmaf(sv.y, kv.x, pi[xi]));
      }
    }
    __syncthreads();                                  // all K reads done before overwrite
#pragma unroll
    for (int xi = 0; xi < 2; ++xi) {
      const int xl = g * 2 + xi;
      KS[xl * 64 + (e ^ xl)] = make_float2(pr[xi], pi[xi]);
    }
  }
  __syncthreads();

  // ---- B3: thread (xs=(t&3)*2, o=t>>2): O[o][x] = sum_e P[x][e]*w[h][e][o][x], 2 x each ----
  {
    const int xs = (threadIdx.x & 3) * 2;   // local x base (block owns global x = xq*8+0..7)
    const int o  = threadIdx.x >> 2;        // 0..63
    float Or[2], Oi[2];
#pragma unroll
    for (int i = 0; i < 2; ++i) { Or[i] = 0.f; Oi[i] = 0.f; }

    const float* __restrict__ w1p = w1 + ((size_t)(h * 64) * 64 + o) * 64 + xq * 8 + xs;
    const float* __restrict__ w2p = w2 + ((size_t)(h * 64) * 64 + o) * 64 + xq * 8 + xs;

#pragma unroll 4
    for (int e = 0; e < 64; ++e) {
      const float2 a1 = *(const float2*)(w1p + (size_t)e * 4096);   // 2 consecutive x
      const float2 a2 = *(const float2*)(w2p + (size_t)e * 4096);
      const float wr[2] = {a1.x, a1.y};
      const float wi[2] = {a2.x, a2.y};
#pragma unroll
      for (int j = 0; j < 2; ++j) {
        const int xl = xs + j;
        const float2 pv = KS[xl * 64 + (e ^ xl)];     // 8 addrs over 32 banks + broadcast
        Or[j] = fmaf(pv.x, wr[j], fmaf(-pv.y, wi[j], Or[j]));
        Oi[j] = fmaf(pv.x, wi[j], fmaf(pv.y, wr[j], Oi[j]));
      }
    }

#pragma unroll
    for (int j = 0; j < 2; ++j) {
      const int xg = xq * 8 + xs + j;
      const float gs = (xg == 0) ? 0x1p-30f : 0x1p-29f;   // 1/(512*512*4096), x2 for m>=1
      coefT[(size_t)(bh * 128 + 2 * xg) * 64 + o]     =  gs * Or[j];
      coefT[(size_t)(bh * 128 + 2 * xg + 1) * 64 + o] = -gs * Oi[j];
    }
  }
}

// Stage C: out[bh][o][t] = sum_j coefT[bh][j][o] * TW[j][t].
__global__ __launch_bounds__(256, 1) void idft_kernel(const float* __restrict__ coefT,
                                                      const float* __restrict__ twj,
                                                      float* __restrict__ out) {
  const int bh = blockIdx.x >> 5;
  const int tc = (blockIdx.x >> 1) & 15;
  const int oh = blockIdx.x & 1;
  const int t  = tc * 256 + threadIdx.x;

  float acc[32];
#pragma unroll
  for (int i = 0; i < 32; ++i) acc[i] = 0.f;

  const float* __restrict__ crow = coefT + (size_t)bh * 8192 + oh * 32;

#pragma unroll 2
  for (int j = 0; j < 128; ++j) {
    const float twv = twj[(size_t)j * 4096 + t];          // coalesced
    const float* __restrict__ cj = crow + (size_t)j * 64; // uniform -> broadcast
#pragma unroll
    for (int qd = 0; qd < 8; ++qd) {
      const float4 c4 = *(const float4*)(cj + qd * 4);
      acc[qd * 4 + 0] = fmaf(c4.x, twv, acc[qd * 4 + 0]);
      acc[qd * 4 + 1] = fmaf(c4.y, twv, acc[qd * 4 + 1]);
      acc[qd * 4 + 2] = fmaf(c4.z, twv, acc[qd * 4 + 2]);
      acc[qd * 4 + 3] = fmaf(c4.w, twv, acc[qd * 4 + 3]);
    }
  }

  float* __restrict__ orow = out + (size_t)bh * 262144 + (size_t)(oh * 32) * 4096 + t;
#pragma unroll
  for (int ol = 0; ol < 32; ++ol) {
    orow[(size_t)ol * 4096] = acc[ol];
  }
}

extern "C" void kernel_launch(void* const* d_in, const int* in_sizes, int n_in,
                              void* d_out, int out_size, void* d_ws, size_t ws_size,
                              hipStream_t stream) {
  (void)in_sizes; (void)n_in; (void)out_size; (void)ws_size;
  const float* q  = (const float*)d_in[0];
  const float* k  = (const float*)d_in[1];
  const float* w1 = (const float*)d_in[3];
  const float* w2 = (const float*)d_in[4];
  float* ws   = (float*)d_ws;
  float* outp = (float*)d_out;

  float* twa   = ws + TWA_OFF;
  float* twj   = ws + TWJ_OFF;
  float* qf    = ws + QF_OFF;
  float* coefT = ws + COEF_OFF;
  float* qfp   = outp;   // 67 MB split-K scratch lives in d_out; idft overwrites it fully

  init_tw<<<256, 256, 0, stream>>>(twa);
  init_twj<<<2048, 256, 0, stream>>>(twj);
  dft_kernel<<<2048, 256, 0, stream>>>(q, k, twa, qfp);
  reduce_kernel<<<1024, 256, 0, stream>>>(qfp, qf);
  attn_kernel<<<512, 256, 0, stream>>>(qf, w1, w2, coefT);
  idft_kernel<<<2048, 256, 0, stream>>>(coefT, twj, outp);
}

// Round 5
// 326.506 us; speedup vs baseline: 1.6957x; 1.6957x over previous
//
#include <hip/hip_runtime.h>
#include <math.h>

// B=8, L=4096, H=8, E=64, MODES=64, C=512. Truncated DFT + tiny complex GEMMs + truncated iDFT.
// v, index_q, index_kv unused by the reference.
// R3 lesson: qfp must stay in ws (33.5 MB) — parking it in d_out pushed the working set past
// the 256 MB L3 (write amplification 10x, FETCH 4x, dft 301 µs). This file = R1 best (332.8 µs)
// with ONE change: dft t-loop software-pipelined in groups of 4 (16 outstanding loads/wave).
// (R4 bench was an infra failure — container died twice; resubmitting unchanged.)

#define Lt 4096
#define Ct 512
#define Mt 64

// ws layout (float offsets)
#define TWA_OFF   0u                      // [1024 t][128]: cos,-sin per mode (512 KB)
#define TWJ_OFF   131072u                 // [128 j][4096 t]: j=2m -> cos, j=2m+1 -> +sin (2 MB)
#define QFP_OFF   655360u                 // [8 chunk][2 src][8 b][64 m][512 c][2]  (33.5 MB)
#define COEF_OFF  9043968u                // coefT: [64 bh][128 j][64 o]  (2 MB)

__global__ __launch_bounds__(256) void init_tw(float* __restrict__ twa) {
  int id = blockIdx.x * 256 + threadIdx.x;   // 65536
  int t = id >> 6, m = id & 63;
  int idx = (m * t) & 4095;
  float a = (float)idx * (1.0f / 2048.0f);
  float s, c;
  sincospif(a, &s, &c);
  twa[t * 128 + 2 * m]     = c;
  twa[t * 128 + 2 * m + 1] = -s;
}

__global__ __launch_bounds__(256) void init_twj(float* __restrict__ twj) {
  int id = blockIdx.x * 256 + threadIdx.x;   // 524288
  int j = id >> 12, t = id & 4095;
  int m = j >> 1;
  int idx = (m * t) & 4095;
  float a = (float)idx * (1.0f / 2048.0f);
  float s, c;
  sincospif(a, &s, &c);
  twj[id] = (j & 1) ? s : c;
}

// Stage A: truncated DFT, radix-4 folded. grid 1024 = mg(2b)|ch(3b)|cblk(1b)|src(1b)|b(3b).
// mg in top bits: the 4 blocks re-reading the same x slab are id, id+256, id+512, id+768 ->
// same (id%8) XCD -> shared L2; q+k stay L3-resident across iterations (FETCH 72 MB << 512 MB
// logical). R4 change: t-loop in groups of 4, register double-buffered -> 16 outstanding
// loads per wave issued a full group ahead (was 4, one step ahead; VALUBusy 40% = latency gap).
__global__ __launch_bounds__(256, 4) void dft_kernel(const float* __restrict__ q,
                                                     const float* __restrict__ k,
                                                     const float* __restrict__ twa,
                                                     float* __restrict__ qfp) {
  const int id   = blockIdx.x;
  const int b    = id & 7;
  const int src  = (id >> 3) & 1;
  const int cblk = (id >> 4) & 1;
  const int ch   = (id >> 5) & 7;            // t-chunk
  const int mg   = (id >> 8) & 3;            // mode quarter: modes [mg*16, mg*16+16)
  const int c    = cblk * 256 + threadIdx.x;
  const float* __restrict__ x = (src ? k : q) + (size_t)b * (Lt * Ct) + c;

  float acc[32];
#pragma unroll
  for (int j = 0; j < 32; ++j) acc[j] = 0.f;

  const int t0 = ch * 128;

  float xb0[16], xb1[16];   // [4 t-steps][4 radix offsets], two buffers

  auto loadg = [&](int tg, float* __restrict__ xb) {
#pragma unroll
    for (int tt = 0; tt < 4; ++tt) {
      const size_t tb = (size_t)(t0 + tg * 4 + tt);
      xb[tt * 4 + 0] = x[tb * Ct];
      xb[tt * 4 + 1] = x[(tb + 1024) * Ct];
      xb[tt * 4 + 2] = x[(tb + 2048) * Ct];
      xb[tt * 4 + 3] = x[(tb + 3072) * Ct];
    }
  };

  auto computeg = [&](int tg, const float* __restrict__ xb) {
#pragma unroll
    for (int tt = 0; tt < 4; ++tt) {
      const float x0 = xb[tt * 4 + 0], x1 = xb[tt * 4 + 1];
      const float x2 = xb[tt * 4 + 2], x3 = xb[tt * 4 + 3];
      const float s02 = x0 + x2, s13 = x1 + x3;
      const float A0v = s02 + s13;
      const float A2v = s02 - s13;
      const float D0v = x0 - x2;
      const float D1v = x1 - x3;

      const int t = t0 + tg * 4 + tt;
      const float4* __restrict__ tw4 = (const float4*)(twa + t * 128 + mg * 32); // uniform
#pragma unroll
      for (int l = 0; l < 4; ++l) {        // 4 mode-quads of this quarter
        const float4 wa = tw4[2 * l + 0];  // modes 4l+0 (re,im), 4l+1 (re,im)
        const float4 wb = tw4[2 * l + 1];  // modes 4l+2, 4l+3
        acc[8 * l + 0] = fmaf(A0v, wa.x, acc[8 * l + 0]);
        acc[8 * l + 1] = fmaf(A0v, wa.y, acc[8 * l + 1]);
        acc[8 * l + 2] = fmaf(D0v, wa.z, fmaf(D1v, wa.w, acc[8 * l + 2]));
        acc[8 * l + 3] = fmaf(D0v, wa.w, fmaf(-D1v, wa.z, acc[8 * l + 3]));
        acc[8 * l + 4] = fmaf(A2v, wb.x, acc[8 * l + 4]);
        acc[8 * l + 5] = fmaf(A2v, wb.y, acc[8 * l + 5]);
        acc[8 * l + 6] = fmaf(D0v, wb.z, fmaf(-D1v, wb.w, acc[8 * l + 6]));
        acc[8 * l + 7] = fmaf(D0v, wb.w, fmaf(D1v, wb.z, acc[8 * l + 7]));
      }
    }
  };

  // 32 groups of 4 t-steps; unrolled by 2 so buffer indices are compile-time (no scratch).
  loadg(0, xb0);
  for (int g2 = 0; g2 < 16; ++g2) {
    loadg(2 * g2 + 1, xb1);            // issue next group's 16 loads
    computeg(2 * g2, xb0);             // compute current under them
    loadg((2 * g2 + 2) & 31, xb0);     // g2=15 wraps to group 0: harmless cached reload
    computeg(2 * g2 + 1, xb1);
  }

  const int chs = ch * 2 + src;
  float* __restrict__ outp = qfp + (size_t)(chs * 8 + b) * 65536 + (size_t)c * 2;
#pragma unroll
  for (int lm = 0; lm < 16; ++lm) {
    const int m = mg * 16 + lm;
    *(float2*)(outp + (size_t)m * 1024) = make_float2(acc[2 * lm], acc[2 * lm + 1]);
  }
}

// Stage B: 256 blocks: each (b,h) split 4-way along Q-mode axis (xq owns modes [xq*16, xq*16+16)).
// Every block loads full K (needed by B1 and B2) + its 16 Q rows. LDS holds interleaved
// complex float2 planes, XOR-swizzled: row r, col c at r*64 + (c ^ (r&31)) -> <=2-way conflicts.
// Grid id = b*32 + h*4 + xq: the 8 blocks sharing a w-slice (same h,xq) differ by 32 -> same XCD.
__global__ __launch_bounds__(256) void attn_kernel(const float* __restrict__ qfp,
                                                   const float* __restrict__ w1,
                                                   const float* __restrict__ w2,
                                                   float* __restrict__ coefT) {
  __shared__ float2 KS[4096];   // K[y][e]; rows 0..15 later overwritten with P[xl][e]
  __shared__ float2 QS[1024];   // Q[xl][e]; after B1 overwritten with S[xl][y]

  const int id = blockIdx.x;
  const int b  = id >> 5;
  const int h  = (id >> 2) & 7;
  const int xq = id & 3;
  const int bh = b * 8 + h;

  const int lane = threadIdx.x & 63;
  const int g    = threadIdx.x >> 6;

  // ---- load: K rows y (all 64), Q rows xl (16 of them); sum 8 split-K partials ----
#pragma unroll 4
  for (int it = 0; it < 16; ++it) {
    const int y = g + 4 * it;
    float kre = 0.f, kim = 0.f;
#pragma unroll
    for (int ch = 0; ch < 8; ++ch) {
      const float2 vk = *(const float2*)(qfp + (size_t)((ch * 2 + 1) * 8 + b) * 65536 +
                                         (size_t)y * 1024 + (size_t)(h * 64 + lane) * 2);
      kre += vk.x; kim += vk.y;
    }
    KS[y * 64 + (lane ^ (y & 31))] = make_float2(kre, kim);
  }
#pragma unroll
  for (int it = 0; it < 4; ++it) {
    const int xl = g + 4 * it;
    const int m  = xq * 16 + xl;
    float qre = 0.f, qim = 0.f;
#pragma unroll
    for (int ch = 0; ch < 8; ++ch) {
      const float2 vq = *(const float2*)(qfp + (size_t)((ch * 2 + 0) * 8 + b) * 65536 +
                                         (size_t)m * 1024 + (size_t)(h * 64 + lane) * 2);
      qre += vq.x; qim += vq.y;
    }
    QS[xl * 64 + (lane ^ xl)] = make_float2(qre, qim);
  }
  __syncthreads();

  // ---- B1: thread (y=lane, g): S[xl][y] = sum_e Q[xl][e]*K[y][e], xl in [g*4, g*4+4) ----
  {
    const int y = lane;
    float sr[4], si[4];
#pragma unroll
    for (int i = 0; i < 4; ++i) { sr[i] = 0.f; si[i] = 0.f; }
    for (int e = 0; e < 64; ++e) {
      const float2 kv = KS[y * 64 + (e ^ (y & 31))];
#pragma unroll
      for (int xi = 0; xi < 4; ++xi) {
        const int xl = g * 4 + xi;
        const float2 qv = QS[xl * 64 + (e ^ xl)];     // wave-uniform -> broadcast
        sr[xi] = fmaf(qv.x, kv.x, fmaf(-qv.y, kv.y, sr[xi]));
        si[xi] = fmaf(qv.x, kv.y, fmaf(qv.y, kv.x, si[xi]));
      }
    }
    __syncthreads();
#pragma unroll
    for (int xi = 0; xi < 4; ++xi) {
      const int xl = g * 4 + xi;
      QS[xl * 64 + (y ^ xl)] = make_float2(tanhf(sr[xi]), tanhf(si[xi]));
    }
  }
  __syncthreads();

  // ---- B2: thread (e=lane, g): P[xl][e] = sum_y S[xl][y]*K[y][e] ----
  {
    const int e = lane;
    float pr[4], pi[4];
#pragma unroll
    for (int i = 0; i < 4; ++i) { pr[i] = 0.f; pi[i] = 0.f; }
    for (int y = 0; y < 64; ++y) {
      const float2 kv = KS[y * 64 + (e ^ (y & 31))];
#pragma unroll
      for (int xi = 0; xi < 4; ++xi) {
        const int xl = g * 4 + xi;
        const float2 sv = QS[xl * 64 + (y ^ xl)];     // wave-uniform -> broadcast
        pr[xi] = fmaf(sv.x, kv.x, fmaf(-sv.y, kv.y, pr[xi]));
        pi[xi] = fmaf(sv.x, kv.y, fmaf(sv.y, kv.x, pi[xi]));
      }
    }
    __syncthreads();                                  // all K reads done before overwrite
#pragma unroll
    for (int xi = 0; xi < 4; ++xi) {
      const int xl = g * 4 + xi;
      KS[xl * 64 + (e ^ xl)] = make_float2(pr[xi], pi[xi]);
    }
  }
  __syncthreads();

  // ---- B3: thread (xs=(t&3)*4, o=t>>2): O[o][x] = sum_e P[x][e]*w[h][e][o][x], 4 x each ----
  {
    const int xs = (threadIdx.x & 3) * 4;   // local x base (block owns global x = xq*16+0..15)
    const int o  = threadIdx.x >> 2;        // 0..63
    float Or[4], Oi[4];
#pragma unroll
    for (int i = 0; i < 4; ++i) { Or[i] = 0.f; Oi[i] = 0.f; }

    const float* __restrict__ w1p = w1 + ((size_t)(h * 64) * 64 + o) * 64 + xq * 16 + xs;
    const float* __restrict__ w2p = w2 + ((size_t)(h * 64) * 64 + o) * 64 + xq * 16 + xs;

#pragma unroll 2
    for (int e = 0; e < 64; ++e) {
      const float4 a1 = *(const float4*)(w1p + (size_t)e * 4096);   // 16 consecutive x -> 64B
      const float4 a2 = *(const float4*)(w2p + (size_t)e * 4096);
      const float wr[4] = {a1.x, a1.y, a1.z, a1.w};
      const float wi[4] = {a2.x, a2.y, a2.z, a2.w};
#pragma unroll
      for (int j = 0; j < 4; ++j) {
        const int xl = xs + j;
        const float2 pv = KS[xl * 64 + (e ^ xl)];     // 16 addrs over 32 banks: conflict-free
        Or[j] = fmaf(pv.x, wr[j], fmaf(-pv.y, wi[j], Or[j]));
        Oi[j] = fmaf(pv.x, wi[j], fmaf(pv.y, wr[j], Oi[j]));
      }
    }

#pragma unroll
    for (int j = 0; j < 4; ++j) {
      const int xg = xq * 16 + xs + j;
      const float gs = (xg == 0) ? 0x1p-30f : 0x1p-29f;   // 1/(512*512*4096), x2 for m>=1
      coefT[(size_t)(bh * 128 + 2 * xg) * 64 + o]     =  gs * Or[j];
      coefT[(size_t)(bh * 128 + 2 * xg + 1) * 64 + o] = -gs * Oi[j];
    }
  }
}

// Stage C: out[bh][o][t] = sum_j coefT[bh][j][o] * TW[j][t].
__global__ __launch_bounds__(256, 1) void idft_kernel(const float* __restrict__ coefT,
                                                      const float* __restrict__ twj,
                                                      float* __restrict__ out) {
  const int bh = blockIdx.x >> 5;
  const int tc = (blockIdx.x >> 1) & 15;
  const int oh = blockIdx.x & 1;
  const int t  = tc * 256 + threadIdx.x;

  float acc[32];
#pragma unroll
  for (int i = 0; i < 32; ++i) acc[i] = 0.f;

  const float* __restrict__ crow = coefT + (size_t)bh * 8192 + oh * 32;

#pragma unroll 2
  for (int j = 0; j < 128; ++j) {
    const float twv = twj[(size_t)j * 4096 + t];          // coalesced
    const float* __restrict__ cj = crow + (size_t)j * 64; // uniform -> broadcast
#pragma unroll
    for (int qd = 0; qd < 8; ++qd) {
      const float4 c4 = *(const float4*)(cj + qd * 4);
      acc[qd * 4 + 0] = fmaf(c4.x, twv, acc[qd * 4 + 0]);
      acc[qd * 4 + 1] = fmaf(c4.y, twv, acc[qd * 4 + 1]);
      acc[qd * 4 + 2] = fmaf(c4.z, twv, acc[qd * 4 + 2]);
      acc[qd * 4 + 3] = fmaf(c4.w, twv, acc[qd * 4 + 3]);
    }
  }

  float* __restrict__ orow = out + (size_t)bh * 262144 + (size_t)(oh * 32) * 4096 + t;
#pragma unroll
  for (int ol = 0; ol < 32; ++ol) {
    orow[(size_t)ol * 4096] = acc[ol];
  }
}

extern "C" void kernel_launch(void* const* d_in, const int* in_sizes, int n_in,
                              void* d_out, int out_size, void* d_ws, size_t ws_size,
                              hipStream_t stream) {
  (void)in_sizes; (void)n_in; (void)out_size; (void)ws_size;
  const float* q  = (const float*)d_in[0];
  const float* k  = (const float*)d_in[1];
  const float* w1 = (const float*)d_in[3];
  const float* w2 = (const float*)d_in[4];
  float* ws   = (float*)d_ws;
  float* outp = (float*)d_out;

  float* twa   = ws + TWA_OFF;
  float* twj   = ws + TWJ_OFF;
  float* qfp   = ws + QFP_OFF;
  float* coefT = ws + COEF_OFF;

  init_tw<<<256, 256, 0, stream>>>(twa);
  init_twj<<<2048, 256, 0, stream>>>(twj);
  dft_kernel<<<1024, 256, 0, stream>>>(q, k, twa, qfp);
  attn_kernel<<<256, 256, 0, stream>>>(qfp, w1, w2, coefT);
  idft_kernel<<<2048, 256, 0, stream>>>(coefT, twj, outp);
}